// Round 8
// baseline (1635.029 us; speedup 1.0000x reference)
//
#include <hip/hip_runtime.h>
#include <cstddef>

#define DIM   1024
#define VOCAB 32000
#define BATCH 2
#define SEQ   2048
#define CTX   4
#define EPS_D 1e-6f
#define LN_EPS 1e-5f

typedef __bf16 bf16x8 __attribute__((ext_vector_type(8)));
typedef float  f32x4  __attribute__((ext_vector_type(4)));
typedef unsigned short ushortx8 __attribute__((ext_vector_type(8)));

// fp32 -> bf16 round-to-nearest-even
__device__ __forceinline__ unsigned short f2bf(float f) {
    unsigned u = __float_as_uint(f);
    u += 0x7fffu + ((u >> 16) & 1u);
    return (unsigned short)(u >> 16);
}
__device__ __forceinline__ float bf2f(unsigned short h) {
    return __uint_as_float((unsigned)h << 16);
}

// async global->LDS, 16B per lane (dest lane-linear; swizzle on GLOBAL source)
#define GL16(gp, lp) __builtin_amdgcn_global_load_lds(                        \
    (const __attribute__((address_space(1))) void*)(gp),                      \
    (__attribute__((address_space(3))) void*)(lp), 16, 0, 0)

// ---------------------------------------------------------------------------
// Embedding gather + local context sum -> hi/lo bf16 split; also seeds den=EPS
// ---------------------------------------------------------------------------
__global__ __launch_bounds__(256)
void embed_split_kernel(const int* __restrict__ x,
                        const float* __restrict__ table,
                        ushort* __restrict__ eh,
                        ushort* __restrict__ el,
                        float* __restrict__ den) {
    int bs = blockIdx.x;
    int b = bs >> 11;
    int s = bs & (SEQ - 1);
    int d = threadIdx.x * 4;
    if (threadIdx.x == 0) den[bs] = EPS_D;     // seed for scores' atomics
    float4 acc = make_float4(0.f, 0.f, 0.f, 0.f);
    #pragma unroll
    for (int o = 0; o < CTX; ++o) {
        int ss = s - o;
        if (ss >= 0) {
            int row = x[b * SEQ + ss];
            const float4 v = *(const float4*)&table[(size_t)row * DIM + d];
            acc.x += v.x; acc.y += v.y; acc.z += v.z; acc.w += v.w;
        }
    }
    ushort4 h, l;
    h.x = f2bf(acc.x); l.x = f2bf(acc.x - bf2f(h.x));
    h.y = f2bf(acc.y); l.y = f2bf(acc.y - bf2f(h.y));
    h.z = f2bf(acc.z); l.z = f2bf(acc.z - bf2f(h.z));
    h.w = f2bf(acc.w); l.w = f2bf(acc.w - bf2f(h.w));
    *(ushort4*)&eh[(size_t)bs * DIM + d] = h;
    *(ushort4*)&el[(size_t)bs * DIM + d] = l;
}

// fp32 version for fallback path
__global__ __launch_bounds__(256)
void embed_ctx_kernel(const int* __restrict__ x,
                      const float* __restrict__ table,
                      float* __restrict__ emb) {
    int bs = blockIdx.x;
    int b = bs >> 11;
    int s = bs & (SEQ - 1);
    int d = threadIdx.x * 4;
    float4 acc = make_float4(0.f, 0.f, 0.f, 0.f);
    #pragma unroll
    for (int o = 0; o < CTX; ++o) {
        int ss = s - o;
        if (ss >= 0) {
            int row = x[b * SEQ + ss];
            const float4 v = *(const float4*)&table[(size_t)row * DIM + d];
            acc.x += v.x; acc.y += v.y; acc.z += v.z; acc.w += v.w;
        }
    }
    *(float4*)&emb[(size_t)bs * DIM + d] = acc;
}

// ---------------------------------------------------------------------------
// transpose + hi/lo split body: W [K][N] fp32 -> th/tl [N][K] bf16
// ---------------------------------------------------------------------------
__device__ __forceinline__ void tsplit_body(const float* __restrict__ W,
                                            ushort* __restrict__ th,
                                            ushort* __restrict__ tl,
                                            int K, int N, int n0, int k0) {
    __shared__ float tile[32][129];
    const int t = threadIdx.x;

    #pragma unroll
    for (int it = 0; it < 4; ++it) {
        int kk = it * 32 + (t >> 3);
        int nn = (t & 7) * 4;
        float4 v4 = *(const float4*)&W[(size_t)(k0 + kk) * N + n0 + nn];
        tile[nn + 0][kk] = v4.x;
        tile[nn + 1][kk] = v4.y;
        tile[nn + 2][kk] = v4.z;
        tile[nn + 3][kk] = v4.w;
    }
    __syncthreads();

    #pragma unroll
    for (int it = 0; it < 2; ++it) {
        int u = it * 256 + t;
        int nn = u >> 4;
        int kc = (u & 15) * 8;
        ushortx8 h, l;
        #pragma unroll
        for (int j = 0; j < 8; ++j) {
            float f = tile[nn][kc + j];
            unsigned short hb = f2bf(f);
            h[j] = hb;
            l[j] = f2bf(f - bf2f(hb));
        }
        size_t off = (size_t)(n0 + nn) * K + k0 + kc;
        *(ushortx8*)&th[off] = h;
        *(ushortx8*)&tl[off] = l;
    }
}

// All 5 weight transposes in ONE launch: blocks 0..7999 -> Wout (1000x8),
// 8000..9023 -> {Wq,Wk,Wv -> qkv concat; Wo} (4 x 32x8)
__global__ __launch_bounds__(256)
void wsplit_all_kernel(const float* __restrict__ Wq, const float* __restrict__ Wk,
                       const float* __restrict__ Wv, const float* __restrict__ Wo,
                       const float* __restrict__ Wout,
                       ushort* __restrict__ qkvTh, ushort* __restrict__ qkvTl,
                       ushort* __restrict__ WoTh,  ushort* __restrict__ WoTl,
                       ushort* __restrict__ WoutTh, ushort* __restrict__ WoutTl) {
    const int bid = blockIdx.x;
    if (bid < 8000) {
        tsplit_body(Wout, WoutTh, WoutTl, DIM, VOCAB,
                    (bid % 1000) * 32, (bid / 1000) * 128);
    } else {
        const int r = bid - 8000;
        const int z = r >> 8;          // 0..3
        const int rr = r & 255;
        const float* W = (z == 0) ? Wq : (z == 1) ? Wk : (z == 2) ? Wv : Wo;
        ushort* th = (z < 3) ? qkvTh + (size_t)z * DIM * DIM : WoTh;
        ushort* tl = (z < 3) ? qkvTl + (size_t)z * DIM * DIM : WoTl;
        tsplit_body(W, th, tl, DIM, DIM, (rr & 31) * 32, (rr >> 5) * 128);
    }
}

// ---------------------------------------------------------------------------
// Generic bf16x3 MFMA GEMM: C = post( Ah@Bh^T + Ah@Bl^T + Al@Bh^T )
// 128x128 tile, BK=32, 4 waves. OM: 0 = fp32 row-major out, 1 = hi/lo split
// row-major via LDS-bounce vectorized stores. SUMROWS: atomicAdd row sums
// into denout (scores path). CAUSAL upper tiles return (never consumed).
// ---------------------------------------------------------------------------
template<int ACT, bool HASB, bool HASDIV, bool CAUSAL, bool TRIK, bool SUMROWS, int OM>
__global__ __launch_bounds__(256, 2)
void mfma3_kernel(const ushort* __restrict__ Ah, const ushort* __restrict__ Al,
                  const ushort* __restrict__ Bh, const ushort* __restrict__ Bl,
                  const float* __restrict__ bias, const float* __restrict__ denp,
                  float* __restrict__ denout,
                  float* __restrict__ Cf, ushort* __restrict__ Ch, ushort* __restrict__ Cl,
                  int M, int N, int K,
                  long long aBat, long long bBat, long long cBat, long long dBat) {
    __shared__ __align__(16) ushort sU[16384];   // staging K-loop; bounce after
    ushort* sAh = sU;
    ushort* sAl = sU + 4096;
    ushort* sBh = sU + 8192;
    ushort* sBl = sU + 12288;

    const int tid = threadIdx.x;
    const int zb = blockIdx.y;
    Ah += (size_t)zb * aBat;  Al += (size_t)zb * aBat;
    Bh += (size_t)zb * bBat;  Bl += (size_t)zb * bBat;
    if (OM == 0) { Cf += (size_t)zb * cBat; }
    else         { Ch += (size_t)zb * cBat; Cl += (size_t)zb * cBat; }
    if (HASDIV) denp += (size_t)zb * dBat;
    if (SUMROWS) denout += (size_t)zb * dBat;

    const int ntn = N >> 7;
    const int mbase = (blockIdx.x / ntn) << 7;
    const int nbase = (blockIdx.x % ntn) << 7;

    if (CAUSAL && nbase > mbase + 127) return;   // never consumed

    const int srl = tid >> 2;
    const int schunk = (tid & 3) ^ ((tid >> 3) & 3);
    const size_t skofs = (size_t)schunk * 8;

    const ushort* gAh0 = Ah + (size_t)(mbase + srl) * K + skofs;
    const ushort* gAh1 = Ah + (size_t)(mbase + 64 + srl) * K + skofs;
    const ushort* gAl0 = Al + (size_t)(mbase + srl) * K + skofs;
    const ushort* gAl1 = Al + (size_t)(mbase + 64 + srl) * K + skofs;
    const ushort* gBh0 = Bh + (size_t)(nbase + srl) * K + skofs;
    const ushort* gBh1 = Bh + (size_t)(nbase + 64 + srl) * K + skofs;
    const ushort* gBl0 = Bl + (size_t)(nbase + srl) * K + skofs;
    const ushort* gBl1 = Bl + (size_t)(nbase + 64 + srl) * K + skofs;

    const int l0 = tid * 8;
    const int l1 = 2048 + tid * 8;

    const int lane = tid & 63;
    const int wid = tid >> 6;
    const int wr = (wid >> 1) * 64;
    const int wc = (wid & 1) * 64;
    const int lrow = lane & 15;
    const int g = lane >> 4;
    int aoff[4], boff[4];
    #pragma unroll
    for (int i = 0; i < 4; ++i) {
        int r = wr + i * 16 + lrow;
        aoff[i] = r * 32 + ((g ^ ((r >> 1) & 3)) << 3);
        int rn = wc + i * 16 + lrow;
        boff[i] = rn * 32 + ((g ^ ((rn >> 1) & 3)) << 3);
    }

    f32x4 acc[4][4];
    #pragma unroll
    for (int i = 0; i < 4; ++i)
        #pragma unroll
        for (int j = 0; j < 4; ++j)
            acc[i][j] = (f32x4){0.f, 0.f, 0.f, 0.f};

    const int ktiles = TRIK ? ((mbase + 128) >> 5) : (K >> 5);
    for (int kt = 0; kt < ktiles; ++kt) {
        GL16(gAh0, sAh + l0);  GL16(gAh1, sAh + l1);
        GL16(gAl0, sAl + l0);  GL16(gAl1, sAl + l1);
        GL16(gBh0, sBh + l0);  GL16(gBh1, sBh + l1);
        GL16(gBl0, sBl + l0);  GL16(gBl1, sBl + l1);
        gAh0 += 32; gAh1 += 32; gAl0 += 32; gAl1 += 32;
        gBh0 += 32; gBh1 += 32; gBl0 += 32; gBl1 += 32;
        __syncthreads();

        bf16x8 fBh[4], fBl[4];
        #pragma unroll
        for (int i = 0; i < 4; ++i) {
            fBh[i] = *(const bf16x8*)(sBh + boff[i]);
            fBl[i] = *(const bf16x8*)(sBl + boff[i]);
        }
        #pragma unroll
        for (int mi = 0; mi < 4; ++mi) {
            bf16x8 ah = *(const bf16x8*)(sAh + aoff[mi]);
            bf16x8 al = *(const bf16x8*)(sAl + aoff[mi]);
            #pragma unroll
            for (int ni = 0; ni < 4; ++ni) {
                acc[mi][ni] = __builtin_amdgcn_mfma_f32_16x16x32_bf16(ah, fBh[ni], acc[mi][ni], 0, 0, 0);
                acc[mi][ni] = __builtin_amdgcn_mfma_f32_16x16x32_bf16(ah, fBl[ni], acc[mi][ni], 0, 0, 0);
                acc[mi][ni] = __builtin_amdgcn_mfma_f32_16x16x32_bf16(al, fBh[ni], acc[mi][ni], 0, 0, 0);
            }
        }
        __syncthreads();
    }

    // C/D layout: col = lane&15, row = (lane>>4)*4 + reg  [m89-verified]
    if (OM == 0) {
        #pragma unroll
        for (int ni = 0; ni < 4; ++ni) {
            const int c = nbase + wc + ni * 16 + lrow;
            float bv = 0.f;
            if (HASB) bv = bias[c];
            #pragma unroll
            for (int mi = 0; mi < 4; ++mi) {
                #pragma unroll
                for (int rg = 0; rg < 4; ++rg) {
                    const int r = mbase + wr + mi * 16 + g * 4 + rg;
                    float vv = acc[mi][ni][rg];
                    if (HASDIV) vv /= denp[r];
                    if (HASB) vv += bv;
                    if (ACT == 1) vv = (vv > 0.f) ? (vv + 1.f) : __expf(vv);
                    Cf[(size_t)r * N + c] = vv;
                }
            }
        }
    } else {
        // LDS-bounce epilogue: scalar LDS writes (XOR-swizzled), b128 global
        // stores. Pass 1: hi (lo kept in acc). Pass 2: lo.
        #pragma unroll
        for (int ni = 0; ni < 4; ++ni) {
            const int cl = wc + ni * 16 + lrow;
            const int c = nbase + cl;
            float bv = 0.f;
            if (HASB) bv = bias[c];
            #pragma unroll
            for (int mi = 0; mi < 4; ++mi) {
                #pragma unroll
                for (int rg = 0; rg < 4; ++rg) {
                    const int rl = wr + mi * 16 + g * 4 + rg;
                    const int r = mbase + rl;
                    float vv = acc[mi][ni][rg];
                    if (HASDIV) vv /= denp[r];
                    if (HASB) vv += bv;
                    if (ACT == 1) vv = (vv > 0.f) ? (vv + 1.f) : __expf(vv);
                    if (CAUSAL && c > r) vv = 0.f;
                    unsigned short hb = f2bf(vv);
                    sU[rl * 128 + (cl ^ ((rl & 15) << 3))] = hb;
                    acc[mi][ni][rg] = vv - bf2f(hb);   // lo for pass 2
                }
            }
        }
        __syncthreads();
        const int orow = tid >> 1;
        const int ohalf = (tid & 1) << 6;
        const int oswz = (orow & 15) << 3;
        float rsum = 0.f;
        {
            const size_t gb = (size_t)(mbase + orow) * N + nbase;
            #pragma unroll
            for (int j = 0; j < 8; ++j) {
                const int cc = ohalf + j * 8;
                ushortx8 v8 = *(const ushortx8*)&sU[orow * 128 + (cc ^ oswz)];
                *(ushortx8*)&Ch[gb + cc] = v8;
                if (SUMROWS) {
                    #pragma unroll
                    for (int t = 0; t < 8; ++t) rsum += bf2f(v8[t]);
                }
            }
        }
        __syncthreads();
        #pragma unroll
        for (int ni = 0; ni < 4; ++ni) {
            const int cl = wc + ni * 16 + lrow;
            #pragma unroll
            for (int mi = 0; mi < 4; ++mi) {
                #pragma unroll
                for (int rg = 0; rg < 4; ++rg) {
                    const int rl = wr + mi * 16 + g * 4 + rg;
                    sU[rl * 128 + (cl ^ ((rl & 15) << 3))] = f2bf(acc[mi][ni][rg]);
                }
            }
        }
        __syncthreads();
        {
            const size_t gb = (size_t)(mbase + orow) * N + nbase;
            #pragma unroll
            for (int j = 0; j < 8; ++j) {
                const int cc = ohalf + j * 8;
                ushortx8 v8 = *(const ushortx8*)&sU[orow * 128 + (cc ^ oswz)];
                *(ushortx8*)&Cl[gb + cc] = v8;
                if (SUMROWS) {
                    #pragma unroll
                    for (int t = 0; t < 8; ++t) rsum += bf2f(v8[t]);
                }
            }
        }
        if (SUMROWS) atomicAdd(&denout[mbase + orow], rsum);
    }
}

// ---------------------------------------------------------------------------
// Fused QKV projection: A = emb hi/lo [4096][1024], B = Wqkv^T hi/lo
// [3072][1024]. nbase 0..7 -> q (elu+1), 8..15 -> k (elu+1), 16..23 -> v
// (linear, TRANSPOSED out [DIM][SEQ] per batch). All epilogues LDS-bounced.
// ---------------------------------------------------------------------------
__global__ __launch_bounds__(256, 2)
void qkvproj_kernel(const ushort* __restrict__ Ah, const ushort* __restrict__ Al,
                    const ushort* __restrict__ Bh, const ushort* __restrict__ Bl,
                    const float* __restrict__ bq, const float* __restrict__ bk,
                    const float* __restrict__ bv_,
                    ushort* __restrict__ qh, ushort* __restrict__ ql,
                    ushort* __restrict__ kh, ushort* __restrict__ kl,
                    ushort* __restrict__ vTh, ushort* __restrict__ vTl) {
    __shared__ __align__(16) ushort sU[16384];
    ushort* sAh = sU;
    ushort* sAl = sU + 4096;
    ushort* sBh = sU + 8192;
    ushort* sBl = sU + 12288;

    const int tid = threadIdx.x;
    const int ntn = 24;
    const int mbase = (blockIdx.x / ntn) << 7;
    const int nbase = (blockIdx.x % ntn) << 7;
    const int mode = nbase >> 10;             // 0 q, 1 k, 2 v (block-uniform)
    const int cb = nbase & 1023;

    const int srl = tid >> 2;
    const int schunk = (tid & 3) ^ ((tid >> 3) & 3);
    const size_t skofs = (size_t)schunk * 8;

    const ushort* gAh0 = Ah + (size_t)(mbase + srl) * DIM + skofs;
    const ushort* gAh1 = Ah + (size_t)(mbase + 64 + srl) * DIM + skofs;
    const ushort* gAl0 = Al + (size_t)(mbase + srl) * DIM + skofs;
    const ushort* gAl1 = Al + (size_t)(mbase + 64 + srl) * DIM + skofs;
    const ushort* gBh0 = Bh + (size_t)(nbase + srl) * DIM + skofs;
    const ushort* gBh1 = Bh + (size_t)(nbase + 64 + srl) * DIM + skofs;
    const ushort* gBl0 = Bl + (size_t)(nbase + srl) * DIM + skofs;
    const ushort* gBl1 = Bl + (size_t)(nbase + 64 + srl) * DIM + skofs;

    const int l0 = tid * 8;
    const int l1 = 2048 + tid * 8;

    const int lane = tid & 63;
    const int wid = tid >> 6;
    const int wr = (wid >> 1) * 64;
    const int wc = (wid & 1) * 64;
    const int lrow = lane & 15;
    const int g = lane >> 4;
    int aoff[4], boff[4];
    #pragma unroll
    for (int i = 0; i < 4; ++i) {
        int r = wr + i * 16 + lrow;
        aoff[i] = r * 32 + ((g ^ ((r >> 1) & 3)) << 3);
        int rn = wc + i * 16 + lrow;
        boff[i] = rn * 32 + ((g ^ ((rn >> 1) & 3)) << 3);
    }

    f32x4 acc[4][4];
    #pragma unroll
    for (int i = 0; i < 4; ++i)
        #pragma unroll
        for (int j = 0; j < 4; ++j)
            acc[i][j] = (f32x4){0.f, 0.f, 0.f, 0.f};

    for (int kt = 0; kt < DIM / 32; ++kt) {
        GL16(gAh0, sAh + l0);  GL16(gAh1, sAh + l1);
        GL16(gAl0, sAl + l0);  GL16(gAl1, sAl + l1);
        GL16(gBh0, sBh + l0);  GL16(gBh1, sBh + l1);
        GL16(gBl0, sBl + l0);  GL16(gBl1, sBl + l1);
        gAh0 += 32; gAh1 += 32; gAl0 += 32; gAl1 += 32;
        gBh0 += 32; gBh1 += 32; gBl0 += 32; gBl1 += 32;
        __syncthreads();

        bf16x8 fBh[4], fBl[4];
        #pragma unroll
        for (int i = 0; i < 4; ++i) {
            fBh[i] = *(const bf16x8*)(sBh + boff[i]);
            fBl[i] = *(const bf16x8*)(sBl + boff[i]);
        }
        #pragma unroll
        for (int mi = 0; mi < 4; ++mi) {
            bf16x8 ah = *(const bf16x8*)(sAh + aoff[mi]);
            bf16x8 al = *(const bf16x8*)(sAl + aoff[mi]);
            #pragma unroll
            for (int ni = 0; ni < 4; ++ni) {
                acc[mi][ni] = __builtin_amdgcn_mfma_f32_16x16x32_bf16(ah, fBh[ni], acc[mi][ni], 0, 0, 0);
                acc[mi][ni] = __builtin_amdgcn_mfma_f32_16x16x32_bf16(ah, fBl[ni], acc[mi][ni], 0, 0, 0);
                acc[mi][ni] = __builtin_amdgcn_mfma_f32_16x16x32_bf16(al, fBh[ni], acc[mi][ni], 0, 0, 0);
            }
        }
        __syncthreads();
    }

    const float* bias = (mode == 0) ? bq : (mode == 1) ? bk : bv_;

    if (mode < 2) {
        ushort* dh = (mode == 0) ? qh : kh;
        ushort* dl = (mode == 0) ? ql : kl;
        // row-major bounce
        #pragma unroll
        for (int ni = 0; ni < 4; ++ni) {
            const int cl = wc + ni * 16 + lrow;
            const float bvv = bias[cb + cl];
            #pragma unroll
            for (int mi = 0; mi < 4; ++mi) {
                #pragma unroll
                for (int rg = 0; rg < 4; ++rg) {
                    const int rl = wr + mi * 16 + g * 4 + rg;
                    float vv = acc[mi][ni][rg] + bvv;
                    vv = (vv > 0.f) ? (vv + 1.f) : __expf(vv);
                    unsigned short hb = f2bf(vv);
                    sU[rl * 128 + (cl ^ ((rl & 15) << 3))] = hb;
                    acc[mi][ni][rg] = vv - bf2f(hb);
                }
            }
        }
        __syncthreads();
        const int orow = tid >> 1;
        const int ohalf = (tid & 1) << 6;
        const int oswz = (orow & 15) << 3;
        {
            const size_t gb = (size_t)(mbase + orow) * DIM + cb;
            #pragma unroll
            for (int j = 0; j < 8; ++j) {
                const int cc = ohalf + j * 8;
                *(ushortx8*)&dh[gb + cc] =
                    *(const ushortx8*)&sU[orow * 128 + (cc ^ oswz)];
            }
        }
        __syncthreads();
        #pragma unroll
        for (int ni = 0; ni < 4; ++ni) {
            const int cl = wc + ni * 16 + lrow;
            #pragma unroll
            for (int mi = 0; mi < 4; ++mi) {
                #pragma unroll
                for (int rg = 0; rg < 4; ++rg) {
                    const int rl = wr + mi * 16 + g * 4 + rg;
                    sU[rl * 128 + (cl ^ ((rl & 15) << 3))] = f2bf(acc[mi][ni][rg]);
                }
            }
        }
        __syncthreads();
        {
            const size_t gb = (size_t)(mbase + orow) * DIM + cb;
            #pragma unroll
            for (int j = 0; j < 8; ++j) {
                const int cc = ohalf + j * 8;
                *(ushortx8*)&dl[gb + cc] =
                    *(const ushortx8*)&sU[orow * 128 + (cc ^ oswz)];
            }
        }
    } else {
        // transposed bounce: write sU[c][r], read rows of v^T vectorized
        #pragma unroll
        for (int ni = 0; ni < 4; ++ni) {
            const int cl = wc + ni * 16 + lrow;
            const float bvv = bias[cb + cl];
            #pragma unroll
            for (int mi = 0; mi < 4; ++mi) {
                #pragma unroll
                for (int rg = 0; rg < 4; ++rg) {
                    const int rl = wr + mi * 16 + g * 4 + rg;
                    float vv = acc[mi][ni][rg] + bvv;
                    unsigned short hb = f2bf(vv);
                    sU[cl * 128 + (rl ^ ((cl & 15) << 3))] = hb;
                    acc[mi][ni][rg] = vv - bf2f(hb);
                }
            }
        }
        __syncthreads();
        const int ocol = tid >> 1;                 // local dim index 0..127
        const int ohalf = (tid & 1) << 6;          // local seq half
        const int oswz = (ocol & 15) << 3;
        const int batch = mbase >> 11;
        const int s0 = mbase & (SEQ - 1);
        {
            const size_t gb = (size_t)batch * DIM * SEQ
                            + (size_t)(cb + ocol) * SEQ + s0;
            #pragma unroll
            for (int j = 0; j < 8; ++j) {
                const int rr = ohalf + j * 8;
                *(ushortx8*)&vTh[gb + rr] =
                    *(const ushortx8*)&sU[ocol * 128 + (rr ^ oswz)];
            }
        }
        __syncthreads();
        #pragma unroll
        for (int ni = 0; ni < 4; ++ni) {
            const int cl = wc + ni * 16 + lrow;
            #pragma unroll
            for (int mi = 0; mi < 4; ++mi) {
                #pragma unroll
                for (int rg = 0; rg < 4; ++rg) {
                    const int rl = wr + mi * 16 + g * 4 + rg;
                    sU[cl * 128 + (rl ^ ((cl & 15) << 3))] = f2bf(acc[mi][ni][rg]);
                }
            }
        }
        __syncthreads();
        {
            const size_t gb = (size_t)batch * DIM * SEQ
                            + (size_t)(cb + ocol) * SEQ + s0;
            #pragma unroll
            for (int j = 0; j < 8; ++j) {
                const int rr = ohalf + j * 8;
                *(ushortx8*)&vTl[gb + rr] =
                    *(const ushortx8*)&sU[ocol * 128 + (rr ^ oswz)];
            }
        }
    }
}

// ---------------------------------------------------------------------------
// Block reduce helper
// ---------------------------------------------------------------------------
__device__ __forceinline__ float block_reduce_sum(float v, float* red) {
    #pragma unroll
    for (int off = 32; off > 0; off >>= 1) v += __shfl_down(v, off);
    const int lane = threadIdx.x & 63;
    const int wid = threadIdx.x >> 6;
    if (lane == 0) red[wid] = v;
    __syncthreads();
    float s = red[0] + red[1] + red[2] + red[3];
    return s;
}

// fp32 den for fallback
__global__ __launch_bounds__(256)
void den_kernel(const float* __restrict__ scores, float* __restrict__ den) {
    const int row = blockIdx.x;
    const int b = row >> 11;
    const int i = row & (SEQ - 1);
    const float* r = scores + (size_t)b * SEQ * SEQ + (size_t)i * SEQ;
    float s = 0.f;
    for (int j = threadIdx.x * 4; j < SEQ; j += 256 * 4) {
        float4 v = *(const float4*)&r[j];
        s += v.x + v.y + v.z + v.w;
    }
    __shared__ float red[4];
    float tot = block_reduce_sum(s, red);
    if (threadIdx.x == 0) den[row] = tot + EPS_D;
}

// ---------------------------------------------------------------------------
// LayerNorm (reads fp32) -> hi/lo bf16 split only
// ---------------------------------------------------------------------------
__global__ __launch_bounds__(256)
void ln_split_kernel(const float* __restrict__ io,
                     const float* __restrict__ gamma,
                     const float* __restrict__ beta,
                     ushort* __restrict__ ahi,
                     ushort* __restrict__ alo) {
    const size_t row = blockIdx.x;
    const float* r = io + row * DIM;
    const int d = threadIdx.x * 4;
    float4 v = *(const float4*)&r[d];
    float s = v.x + v.y + v.z + v.w;
    float sq = v.x * v.x + v.y * v.y + v.z * v.z + v.w * v.w;
    __shared__ float r1[4];
    __shared__ float r2[4];
    float tot = block_reduce_sum(s, r1);
    __syncthreads();
    float totsq = block_reduce_sum(sq, r2);
    const float mu = tot * (1.f / DIM);
    const float var = totsq * (1.f / DIM) - mu * mu;
    const float rs = rsqrtf(var + LN_EPS);
    float4 gv = *(const float4*)&gamma[d];
    float4 bv = *(const float4*)&beta[d];
    v.x = (v.x - mu) * rs * gv.x + bv.x;
    v.y = (v.y - mu) * rs * gv.y + bv.y;
    v.z = (v.z - mu) * rs * gv.z + bv.z;
    v.w = (v.w - mu) * rs * gv.w + bv.w;
    ushort4 h, l;
    h.x = f2bf(v.x); l.x = f2bf(v.x - bf2f(h.x));
    h.y = f2bf(v.y); l.y = f2bf(v.y - bf2f(h.y));
    h.z = f2bf(v.z); l.z = f2bf(v.z - bf2f(h.z));
    h.w = f2bf(v.w); l.w = f2bf(v.w - bf2f(h.w));
    *(ushort4*)&ahi[row * DIM + d] = h;
    *(ushort4*)&alo[row * DIM + d] = l;
}

// fp32 LN (fallback)
__global__ __launch_bounds__(256)
void ln_kernel(float* __restrict__ io,
               const float* __restrict__ gamma,
               const float* __restrict__ beta) {
    const size_t row = blockIdx.x;
    float* r = io + row * DIM;
    const int d = threadIdx.x * 4;
    float4 v = *(const float4*)&r[d];
    float s = v.x + v.y + v.z + v.w;
    float sq = v.x * v.x + v.y * v.y + v.z * v.z + v.w * v.w;
    __shared__ float r1[4];
    __shared__ float r2[4];
    float tot = block_reduce_sum(s, r1);
    __syncthreads();
    float totsq = block_reduce_sum(sq, r2);
    const float mu = tot * (1.f / DIM);
    const float var = totsq * (1.f / DIM) - mu * mu;
    const float rs = rsqrtf(var + LN_EPS);
    float4 gv = *(const float4*)&gamma[d];
    float4 bv = *(const float4*)&beta[d];
    v.x = (v.x - mu) * rs * gv.x + bv.x;
    v.y = (v.y - mu) * rs * gv.y + bv.y;
    v.z = (v.z - mu) * rs * gv.z + bv.z;
    v.w = (v.w - mu) * rs * gv.w + bv.w;
    *(float4*)&r[d] = v;
}

// ---------------------------------------------------------------------------
// Logits kernel (unchanged — control). XCD stripe swizzle + non-temporal C.
// ---------------------------------------------------------------------------
__global__ __launch_bounds__(256, 2)
void logits_mfma_kernel(const ushort* __restrict__ Ahi,
                        const ushort* __restrict__ Alo,
                        const ushort* __restrict__ Bhi,
                        const ushort* __restrict__ Blo,
                        const float* __restrict__ bias,
                        float* __restrict__ C) {
    __shared__ __align__(16) ushort sAh[4096];
    __shared__ __align__(16) ushort sAl[4096];
    __shared__ __align__(16) ushort sBh[4096];
    __shared__ __align__(16) ushort sBl[4096];

    const int tid = threadIdx.x;
    const int bid = blockIdx.x;
    const int xcd = bid & 7;
    const int idx = bid >> 3;                 // 0..999
    const int mbase = ((xcd << 2) | (idx & 3)) * 128;  // 32 m-tiles
    const int nbase = (idx >> 2) * 128;                // 250 n-tiles

    const int srl = tid >> 2;
    const int schunk = (tid & 3) ^ ((tid >> 3) & 3);
    const size_t skofs = (size_t)schunk * 8;

    const ushort* gAh0 = Ahi + (size_t)(mbase + srl) * DIM + skofs;
    const ushort* gAh1 = Ahi + (size_t)(mbase + 64 + srl) * DIM + skofs;
    const ushort* gAl0 = Alo + (size_t)(mbase + srl) * DIM + skofs;
    const ushort* gAl1 = Alo + (size_t)(mbase + 64 + srl) * DIM + skofs;
    const ushort* gBh0 = Bhi + (size_t)(nbase + srl) * DIM + skofs;
    const ushort* gBh1 = Bhi + (size_t)(nbase + 64 + srl) * DIM + skofs;
    const ushort* gBl0 = Blo + (size_t)(nbase + srl) * DIM + skofs;
    const ushort* gBl1 = Blo + (size_t)(nbase + 64 + srl) * DIM + skofs;

    const int l0 = tid * 8;
    const int l1 = 2048 + tid * 8;

    const int lane = tid & 63;
    const int wid = tid >> 6;
    const int wr = (wid >> 1) * 64;
    const int wc = (wid & 1) * 64;
    const int lrow = lane & 15;
    const int g = lane >> 4;
    int aoff[4], boff[4];
    #pragma unroll
    for (int i = 0; i < 4; ++i) {
        int r = wr + i * 16 + lrow;
        aoff[i] = r * 32 + ((g ^ ((r >> 1) & 3)) << 3);
        int rn = wc + i * 16 + lrow;
        boff[i] = rn * 32 + ((g ^ ((rn >> 1) & 3)) << 3);
    }

    f32x4 acc[4][4];
    #pragma unroll
    for (int i = 0; i < 4; ++i)
        #pragma unroll
        for (int j = 0; j < 4; ++j)
            acc[i][j] = (f32x4){0.f, 0.f, 0.f, 0.f};

    for (int kt = 0; kt < DIM / 32; ++kt) {
        GL16(gAh0, sAh + l0);  GL16(gAh1, sAh + l1);
        GL16(gAl0, sAl + l0);  GL16(gAl1, sAl + l1);
        GL16(gBh0, sBh + l0);  GL16(gBh1, sBh + l1);
        GL16(gBl0, sBl + l0);  GL16(gBl1, sBl + l1);
        gAh0 += 32; gAh1 += 32; gAl0 += 32; gAl1 += 32;
        gBh0 += 32; gBh1 += 32; gBl0 += 32; gBl1 += 32;
        __syncthreads();

        bf16x8 fBh[4], fBl[4];
        #pragma unroll
        for (int i = 0; i < 4; ++i) {
            fBh[i] = *(const bf16x8*)(sBh + boff[i]);
            fBl[i] = *(const bf16x8*)(sBl + boff[i]);
        }
        #pragma unroll
        for (int mi = 0; mi < 4; ++mi) {
            bf16x8 ah = *(const bf16x8*)(sAh + aoff[mi]);
            bf16x8 al = *(const bf16x8*)(sAl + aoff[mi]);
            #pragma unroll
            for (int ni = 0; ni < 4; ++ni) {
                acc[mi][ni] = __builtin_amdgcn_mfma_f32_16x16x32_bf16(ah, fBh[ni], acc[mi][ni], 0, 0, 0);
                acc[mi][ni] = __builtin_amdgcn_mfma_f32_16x16x32_bf16(ah, fBl[ni], acc[mi][ni], 0, 0, 0);
                acc[mi][ni] = __builtin_amdgcn_mfma_f32_16x16x32_bf16(al, fBh[ni], acc[mi][ni], 0, 0, 0);
            }
        }
        __syncthreads();
    }

    #pragma unroll
    for (int ni = 0; ni < 4; ++ni) {
        const int c = nbase + wc + ni * 16 + lrow;
        const float bv = bias[c];
        #pragma unroll
        for (int mi = 0; mi < 4; ++mi) {
            #pragma unroll
            for (int rg = 0; rg < 4; ++rg) {
                const int r = mbase + wr + mi * 16 + g * 4 + rg;
                __builtin_nontemporal_store(acc[mi][ni][rg] + bv,
                                            &C[(size_t)r * VOCAB + c]);
            }
        }
    }
}

// ---------------------------------------------------------------------------
// Fallback fp32 GEMM + scores (used only if workspace too small)
// ---------------------------------------------------------------------------
template<int ACT, bool HAS_BIAS, bool HAS_DIV>
__global__ __launch_bounds__(256)
void gemm_kernel(const float* __restrict__ A,
                 const float* __restrict__ B,
                 const float* __restrict__ bias,
                 const float* __restrict__ rowdiv,
                 float* __restrict__ C,
                 int M, int N, int K) {
    __shared__ float As[16][64];
    __shared__ float Bs[16][64];

    const int tid = threadIdx.x;
    const int tx = tid & 15;
    const int ty = tid >> 4;
    const int row0 = blockIdx.y * 64;
    const int col0 = blockIdx.x * 64;

    const int a_row = tid >> 2;
    const int a_col = (tid & 3) * 4;
    const int b_row = tid >> 4;
    const int b_col = (tid & 15) * 4;

    const float* Aptr = A + (size_t)(row0 + a_row) * K + a_col;
    const float* Bptr = B + (size_t)b_row * N + col0 + b_col;

    float acc[4][4];
    #pragma unroll
    for (int i = 0; i < 4; ++i)
        #pragma unroll
        for (int j = 0; j < 4; ++j) acc[i][j] = 0.f;

    for (int k0 = 0; k0 < K; k0 += 16) {
        float4 a4 = *(const float4*)(Aptr + k0);
        float4 b4 = *(const float4*)(Bptr + (size_t)k0 * N);
        As[a_col + 0][a_row] = a4.x;
        As[a_col + 1][a_row] = a4.y;
        As[a_col + 2][a_row] = a4.z;
        As[a_col + 3][a_row] = a4.w;
        *(float4*)&Bs[b_row][b_col] = b4;
        __syncthreads();
        #pragma unroll
        for (int kk = 0; kk < 16; ++kk) {
            float4 av = *(const float4*)&As[kk][ty * 4];
            float4 bv = *(const float4*)&Bs[kk][tx * 4];
            float am[4] = {av.x, av.y, av.z, av.w};
            float bm[4] = {bv.x, bv.y, bv.z, bv.w};
            #pragma unroll
            for (int i = 0; i < 4; ++i)
                #pragma unroll
                for (int j = 0; j < 4; ++j)
                    acc[i][j] = fmaf(am[i], bm[j], acc[i][j]);
        }
        __syncthreads();
    }

    #pragma unroll
    for (int i = 0; i < 4; ++i) {
        const int r = row0 + ty * 4 + i;
        float rdiv = 1.f;
        if (HAS_DIV) rdiv = 1.f / rowdiv[r];
        #pragma unroll
        for (int j = 0; j < 4; ++j) {
            const int c = col0 + tx * 4 + j;
            float v = acc[i][j] * rdiv;
            if (HAS_BIAS) v += bias[c];
            if (ACT == 1) v = (v > 0.f) ? (v + 1.f) : __expf(v);
            C[(size_t)r * N + c] = v;
        }
    }
}

__global__ __launch_bounds__(256)
void scores_kernel(const float* __restrict__ q,
                   const float* __restrict__ k,
                   float* __restrict__ scores) {
    const int b = blockIdx.z;
    const int tid = threadIdx.x;
    const int tx = tid & 15;
    const int ty = tid >> 4;
    const int i0 = blockIdx.y * 64;
    const int j0 = blockIdx.x * 64;
    float* Sc = scores + (size_t)b * SEQ * SEQ;

    if (j0 > i0 + 63) {
        #pragma unroll
        for (int i = 0; i < 4; ++i)
            #pragma unroll
            for (int j = 0; j < 4; ++j)
                Sc[(size_t)(i0 + ty * 4 + i) * SEQ + j0 + tx * 4 + j] = 0.f;
        return;
    }

    const float* Q = q + (size_t)b * SEQ * DIM;
    const float* Kp = k + (size_t)b * SEQ * DIM;

    __shared__ float Qs[16][64];
    __shared__ float Ks[16][64];

    const int l_row = tid >> 2;
    const int l_col = (tid & 3) * 4;

    const float* Qptr = Q + (size_t)(i0 + l_row) * DIM + l_col;
    const float* Kptr = Kp + (size_t)(j0 + l_row) * DIM + l_col;

    float acc[4][4];
    #pragma unroll
    for (int i = 0; i < 4; ++i)
        #pragma unroll
        for (int j = 0; j < 4; ++j) acc[i][j] = 0.f;

    for (int d0 = 0; d0 < DIM; d0 += 16) {
        float4 a4 = *(const float4*)(Qptr + d0);
        float4 b4 = *(const float4*)(Kptr + d0);
        Qs[l_col + 0][l_row] = a4.x;
        Qs[l_col + 1][l_row] = a4.y;
        Qs[l_col + 2][l_row] = a4.z;
        Qs[l_col + 3][l_row] = a4.w;
        Ks[l_col + 0][l_row] = b4.x;
        Ks[l_col + 1][l_row] = b4.y;
        Ks[l_col + 2][l_row] = b4.z;
        Ks[l_col + 3][l_row] = b4.w;
        __syncthreads();
        #pragma unroll
        for (int kk = 0; kk < 16; ++kk) {
            float4 av = *(const float4*)&Qs[kk][ty * 4];
            float4 bv = *(const float4*)&Ks[kk][tx * 4];
            float am[4] = {av.x, av.y, av.z, av.w};
            float bm[4] = {bv.x, bv.y, bv.z, bv.w};
            #pragma unroll
            for (int i = 0; i < 4; ++i)
                #pragma unroll
                for (int j = 0; j < 4; ++j)
                    acc[i][j] = fmaf(am[i], bm[j], acc[i][j]);
        }
        __syncthreads();
    }

    #pragma unroll
    for (int i = 0; i < 4; ++i) {
        const int ii = i0 + ty * 4 + i;
        #pragma unroll
        for (int j = 0; j < 4; ++j) {
            const int jj = j0 + tx * 4 + j;
            Sc[(size_t)ii * SEQ + jj] = (jj <= ii) ? acc[i][j] : 0.f;
        }
    }
}

// ---------------------------------------------------------------------------
// Host launch
// ---------------------------------------------------------------------------
extern "C" void kernel_launch(void* const* d_in, const int* in_sizes, int n_in,
                              void* d_out, int out_size, void* d_ws, size_t ws_size,
                              hipStream_t stream) {
    const int*   x     = (const int*)d_in[0];
    const float* table = (const float*)d_in[1];
    const float* Wq    = (const float*)d_in[2];
    const float* bq    = (const float*)d_in[3];
    const float* Wk    = (const float*)d_in[4];
    const float* bk    = (const float*)d_in[5];
    const float* Wv    = (const float*)d_in[6];
    const float* bv    = (const float*)d_in[7];
    const float* Wo    = (const float*)d_in[8];
    const float* bo    = (const float*)d_in[9];
    const float* gamma = (const float*)d_in[10];
    const float* beta  = (const float*)d_in[11];
    const float* Wout  = (const float*)d_in[12];
    const float* bout  = (const float*)d_in[13];
    float* logits = (float*)d_out;

    const int M = BATCH * SEQ;                 // 4096

    // ---- workspace layout (identical to round-5 proven budget)
    char* p = (char*)d_ws;
    auto alloc = [&](size_t bytes) { char* r = p; p += bytes; return r; };
    ushort* WoutTh = (ushort*)alloc((size_t)VOCAB * DIM * 2);   // 65.5 MB
    ushort* WoutTl = (ushort*)alloc((size_t)VOCAB * DIM * 2);
    ushort* ehi    = (ushort*)alloc((size_t)M * DIM * 2);       // 8.39 MB
    ushort* elo    = (ushort*)alloc((size_t)M * DIM * 2);
    ushort* WqkvTh = (ushort*)alloc((size_t)3 * DIM * DIM * 2); // concat q|k|v
    ushort* WqkvTl = (ushort*)alloc((size_t)3 * DIM * DIM * 2);
    ushort* WoTh   = (ushort*)alloc((size_t)DIM * DIM * 2);
    ushort* WoTl   = (ushort*)alloc((size_t)DIM * DIM * 2);
    ushort* qhi    = (ushort*)alloc((size_t)M * DIM * 2);
    ushort* qlo    = (ushort*)alloc((size_t)M * DIM * 2);
    ushort* khi    = (ushort*)alloc((size_t)M * DIM * 2);
    ushort* klo    = (ushort*)alloc((size_t)M * DIM * 2);
    ushort* vTh    = (ushort*)alloc((size_t)BATCH * DIM * SEQ * 2);
    ushort* vTl    = (ushort*)alloc((size_t)BATCH * DIM * SEQ * 2);
    ushort* shi    = (ushort*)alloc((size_t)BATCH * SEQ * SEQ * 2); // 16.8 MB
    ushort* slo    = (ushort*)alloc((size_t)BATCH * SEQ * SEQ * 2);
    float*  den    = (float*)alloc((size_t)M * 4);
    const size_t need = (size_t)(p - (char*)d_ws);

    // aliases (liveness-checked): q dead after scores, k dead after scores,
    // e dead after qkv-proj
    ushort* attnh = qhi;
    ushort* attnl = qlo;
    float*  outf  = (float*)khi;               // spans khi+klo = 16.78 MB
    ushort* ahi   = ehi;
    ushort* alo   = elo;

    if (ws_size >= need) {
        // ---- MFMA pipeline ----
        // 0. ALL weight transpose+splits in one launch
        wsplit_all_kernel<<<8000 + 1024, 256, 0, stream>>>(
            Wq, Wk, Wv, Wo, Wout, WqkvTh, WqkvTl, WoTh, WoTl, WoutTh, WoutTl);

        // 1. embedding + local context -> hi/lo (also seeds den = EPS)
        embed_split_kernel<<<M, 256, 0, stream>>>(x, table, ehi, elo, den);

        // 2. fused q,k,v projection (one launch, 768 blocks)
        qkvproj_kernel<<<(M / 128) * 24, 256, 0, stream>>>(
            ehi, elo, WqkvTh, WqkvTl, bq, bk, bv,
            qhi, qlo, khi, klo, vTh, vTl);

        // 3. causal scores (hi/lo out) + den via per-tile row-sum atomics
        mfma3_kernel<0, false, false, true, false, true, 1>
            <<<dim3((SEQ / 128) * (SEQ / 128), BATCH), 256, 0, stream>>>(
            qhi, qlo, khi, klo, nullptr, nullptr, den, nullptr, shi, slo,
            SEQ, SEQ, DIM,
            (long long)SEQ * DIM, (long long)SEQ * DIM, (long long)SEQ * SEQ,
            (long long)SEQ);

        // 4. num = scores @ v / den  (triangular K-stop; attn hi/lo out)
        mfma3_kernel<0, false, true, false, true, false, 1>
            <<<dim3((SEQ / 128) * (DIM / 128), BATCH), 256, 0, stream>>>(
            shi, slo, vTh, vTl, nullptr, den, nullptr, nullptr, attnh, attnl,
            SEQ, DIM, SEQ,
            (long long)SEQ * SEQ, (long long)DIM * SEQ, (long long)SEQ * DIM,
            (long long)SEQ);

        // 5. out = attn @ Wo + bo  (fp32 out for LN)
        mfma3_kernel<0, true, false, false, false, false, 0>
            <<<dim3((M / 128) * (DIM / 128), 1), 256, 0, stream>>>(
            attnh, attnl, WoTh, WoTl, bo, nullptr, nullptr, outf, nullptr, nullptr,
            M, DIM, DIM, 0, 0, 0, 0);

        // 6. LayerNorm -> hi/lo split
        ln_split_kernel<<<M, 256, 0, stream>>>(outf, gamma, beta, ahi, alo);

        // 7. logits (XCD stripe swizzle)
        logits_mfma_kernel<<<(M / 128) * (VOCAB / 128), 256, 0, stream>>>(
            ahi, alo, WoutTh, WoutTl, bout, logits);
    } else {
        // ---- fp32 fallback pipeline (never expected; safety) ----
        const size_t NE = (size_t)M * DIM;
        float* ws    = (float*)d_ws;
        float* emb   = ws;
        float* q     = ws + NE;
        float* k     = ws + 2 * NE;
        float* v     = ws + 3 * NE;
        float* sc    = ws + 4 * NE;
        float* denf  = sc + (size_t)BATCH * SEQ * SEQ;
        float* attn  = emb;
        float* out   = q;

        embed_ctx_kernel<<<M, 256, 0, stream>>>(x, table, emb);
        dim3 gq(DIM / 64, M / 64);
        gemm_kernel<1, true, false><<<gq, 256, 0, stream>>>(emb, Wq, bq, nullptr, q, M, DIM, DIM);
        gemm_kernel<1, true, false><<<gq, 256, 0, stream>>>(emb, Wk, bk, nullptr, k, M, DIM, DIM);
        gemm_kernel<0, true, false><<<gq, 256, 0, stream>>>(emb, Wv, bv, nullptr, v, M, DIM, DIM);
        dim3 gs(SEQ / 64, SEQ / 64, BATCH);
        scores_kernel<<<gs, 256, 0, stream>>>(q, k, sc);
        den_kernel<<<M, 256, 0, stream>>>(sc, denf);
        dim3 gn(DIM / 64, SEQ / 64);
        for (int b = 0; b < BATCH; ++b) {
            gemm_kernel<0, false, true><<<gn, 256, 0, stream>>>(
                sc + (size_t)b * SEQ * SEQ, v + (size_t)b * SEQ * DIM,
                nullptr, denf + (size_t)b * SEQ,
                attn + (size_t)b * SEQ * DIM, SEQ, DIM, SEQ);
        }
        gemm_kernel<0, true, false><<<gq, 256, 0, stream>>>(attn, Wo, bo, nullptr, out, M, DIM, DIM);
        ln_kernel<<<M, 256, 0, stream>>>(out, gamma, beta);
        dim3 gl(VOCAB / 64, M / 64);
        gemm_kernel<0, true, false><<<gl, 256, 0, stream>>>(out, Wout, bout, nullptr, logits, M, VOCAB, DIM);
    }
}

// Round 9
// 1558.913 us; speedup vs baseline: 1.0488x; 1.0488x over previous
//
#include <hip/hip_runtime.h>
#include <cstddef>

#define DIM   1024
#define VOCAB 32000
#define BATCH 2
#define SEQ   2048
#define CTX   4
#define EPS_D 1e-6f
#define LN_EPS 1e-5f

typedef __bf16 bf16x8 __attribute__((ext_vector_type(8)));
typedef float  f32x4  __attribute__((ext_vector_type(4)));
typedef unsigned short ushortx8 __attribute__((ext_vector_type(8)));

// fp32 -> bf16 round-to-nearest-even
__device__ __forceinline__ unsigned short f2bf(float f) {
    unsigned u = __float_as_uint(f);
    u += 0x7fffu + ((u >> 16) & 1u);
    return (unsigned short)(u >> 16);
}
__device__ __forceinline__ float bf2f(unsigned short h) {
    return __uint_as_float((unsigned)h << 16);
}

// async global->LDS, 16B per lane (dest lane-linear; swizzle on GLOBAL source)
#define GL16(gp, lp) __builtin_amdgcn_global_load_lds(                        \
    (const __attribute__((address_space(1))) void*)(gp),                      \
    (__attribute__((address_space(3))) void*)(lp), 16, 0, 0)

// ---------------------------------------------------------------------------
// Embedding gather + local context sum -> hi/lo bf16 split; also seeds den=EPS
// ---------------------------------------------------------------------------
__global__ __launch_bounds__(256)
void embed_split_kernel(const int* __restrict__ x,
                        const float* __restrict__ table,
                        ushort* __restrict__ eh,
                        ushort* __restrict__ el,
                        float* __restrict__ den) {
    int bs = blockIdx.x;
    int b = bs >> 11;
    int s = bs & (SEQ - 1);
    int d = threadIdx.x * 4;
    if (threadIdx.x == 0) den[bs] = EPS_D;     // seed for scores' atomics
    float4 acc = make_float4(0.f, 0.f, 0.f, 0.f);
    #pragma unroll
    for (int o = 0; o < CTX; ++o) {
        int ss = s - o;
        if (ss >= 0) {
            int row = x[b * SEQ + ss];
            const float4 v = *(const float4*)&table[(size_t)row * DIM + d];
            acc.x += v.x; acc.y += v.y; acc.z += v.z; acc.w += v.w;
        }
    }
    ushort4 h, l;
    h.x = f2bf(acc.x); l.x = f2bf(acc.x - bf2f(h.x));
    h.y = f2bf(acc.y); l.y = f2bf(acc.y - bf2f(h.y));
    h.z = f2bf(acc.z); l.z = f2bf(acc.z - bf2f(h.z));
    h.w = f2bf(acc.w); l.w = f2bf(acc.w - bf2f(h.w));
    *(ushort4*)&eh[(size_t)bs * DIM + d] = h;
    *(ushort4*)&el[(size_t)bs * DIM + d] = l;
}

// fp32 version for fallback path
__global__ __launch_bounds__(256)
void embed_ctx_kernel(const int* __restrict__ x,
                      const float* __restrict__ table,
                      float* __restrict__ emb) {
    int bs = blockIdx.x;
    int b = bs >> 11;
    int s = bs & (SEQ - 1);
    int d = threadIdx.x * 4;
    float4 acc = make_float4(0.f, 0.f, 0.f, 0.f);
    #pragma unroll
    for (int o = 0; o < CTX; ++o) {
        int ss = s - o;
        if (ss >= 0) {
            int row = x[b * SEQ + ss];
            const float4 v = *(const float4*)&table[(size_t)row * DIM + d];
            acc.x += v.x; acc.y += v.y; acc.z += v.z; acc.w += v.w;
        }
    }
    *(float4*)&emb[(size_t)bs * DIM + d] = acc;
}

// ---------------------------------------------------------------------------
// transpose + hi/lo split body: W [K][N] fp32 -> th/tl [N][K] bf16
// ---------------------------------------------------------------------------
__device__ __forceinline__ void tsplit_body(const float* __restrict__ W,
                                            ushort* __restrict__ th,
                                            ushort* __restrict__ tl,
                                            int K, int N, int n0, int k0) {
    __shared__ float tile[32][129];
    const int t = threadIdx.x;

    #pragma unroll
    for (int it = 0; it < 4; ++it) {
        int kk = it * 32 + (t >> 3);
        int nn = (t & 7) * 4;
        float4 v4 = *(const float4*)&W[(size_t)(k0 + kk) * N + n0 + nn];
        tile[nn + 0][kk] = v4.x;
        tile[nn + 1][kk] = v4.y;
        tile[nn + 2][kk] = v4.z;
        tile[nn + 3][kk] = v4.w;
    }
    __syncthreads();

    #pragma unroll
    for (int it = 0; it < 2; ++it) {
        int u = it * 256 + t;
        int nn = u >> 4;
        int kc = (u & 15) * 8;
        ushortx8 h, l;
        #pragma unroll
        for (int j = 0; j < 8; ++j) {
            float f = tile[nn][kc + j];
            unsigned short hb = f2bf(f);
            h[j] = hb;
            l[j] = f2bf(f - bf2f(hb));
        }
        size_t off = (size_t)(n0 + nn) * K + k0 + kc;
        *(ushortx8*)&th[off] = h;
        *(ushortx8*)&tl[off] = l;
    }
}

// All 5 weight transposes in ONE launch: blocks 0..7999 -> Wout (1000x8),
// 8000..9023 -> {Wq,Wk,Wv -> qkv concat; Wo} (4 x 32x8)
__global__ __launch_bounds__(256)
void wsplit_all_kernel(const float* __restrict__ Wq, const float* __restrict__ Wk,
                       const float* __restrict__ Wv, const float* __restrict__ Wo,
                       const float* __restrict__ Wout,
                       ushort* __restrict__ qkvTh, ushort* __restrict__ qkvTl,
                       ushort* __restrict__ WoTh,  ushort* __restrict__ WoTl,
                       ushort* __restrict__ WoutTh, ushort* __restrict__ WoutTl) {
    const int bid = blockIdx.x;
    if (bid < 8000) {
        tsplit_body(Wout, WoutTh, WoutTl, DIM, VOCAB,
                    (bid % 1000) * 32, (bid / 1000) * 128);
    } else {
        const int r = bid - 8000;
        const int z = r >> 8;          // 0..3
        const int rr = r & 255;
        const float* W = (z == 0) ? Wq : (z == 1) ? Wk : (z == 2) ? Wv : Wo;
        ushort* th = (z < 3) ? qkvTh + (size_t)z * DIM * DIM : WoTh;
        ushort* tl = (z < 3) ? qkvTl + (size_t)z * DIM * DIM : WoTl;
        tsplit_body(W, th, tl, DIM, DIM, (rr & 31) * 32, (rr >> 5) * 128);
    }
}

// ---------------------------------------------------------------------------
// Generic bf16x3 MFMA GEMM: C = post( Ah@Bh^T + Ah@Bl^T + Al@Bh^T )
// 128x128 tile, BK=32, 4 waves. OM: 0 = fp32 row-major out, 1 = hi/lo split
// row-major via LDS-bounce vectorized stores. SUMROWS: atomicAdd row sums
// into denout (scores path). CAUSAL upper tiles return (never consumed).
// ---------------------------------------------------------------------------
template<int ACT, bool HASB, bool HASDIV, bool CAUSAL, bool TRIK, bool SUMROWS, int OM>
__global__ __launch_bounds__(256, 2)
void mfma3_kernel(const ushort* __restrict__ Ah, const ushort* __restrict__ Al,
                  const ushort* __restrict__ Bh, const ushort* __restrict__ Bl,
                  const float* __restrict__ bias, const float* __restrict__ denp,
                  float* __restrict__ denout,
                  float* __restrict__ Cf, ushort* __restrict__ Ch, ushort* __restrict__ Cl,
                  int M, int N, int K,
                  long long aBat, long long bBat, long long cBat, long long dBat) {
    __shared__ __align__(16) ushort sU[16384];   // staging K-loop; bounce after
    ushort* sAh = sU;
    ushort* sAl = sU + 4096;
    ushort* sBh = sU + 8192;
    ushort* sBl = sU + 12288;

    const int tid = threadIdx.x;
    const int zb = blockIdx.y;
    Ah += (size_t)zb * aBat;  Al += (size_t)zb * aBat;
    Bh += (size_t)zb * bBat;  Bl += (size_t)zb * bBat;
    if (OM == 0) { Cf += (size_t)zb * cBat; }
    else         { Ch += (size_t)zb * cBat; Cl += (size_t)zb * cBat; }
    if (HASDIV) denp += (size_t)zb * dBat;
    if (SUMROWS) denout += (size_t)zb * dBat;

    const int ntn = N >> 7;
    const int mbase = (blockIdx.x / ntn) << 7;
    const int nbase = (blockIdx.x % ntn) << 7;

    if (CAUSAL && nbase > mbase + 127) return;   // never consumed

    const int srl = tid >> 2;
    const int schunk = (tid & 3) ^ ((tid >> 3) & 3);
    const size_t skofs = (size_t)schunk * 8;

    const ushort* gAh0 = Ah + (size_t)(mbase + srl) * K + skofs;
    const ushort* gAh1 = Ah + (size_t)(mbase + 64 + srl) * K + skofs;
    const ushort* gAl0 = Al + (size_t)(mbase + srl) * K + skofs;
    const ushort* gAl1 = Al + (size_t)(mbase + 64 + srl) * K + skofs;
    const ushort* gBh0 = Bh + (size_t)(nbase + srl) * K + skofs;
    const ushort* gBh1 = Bh + (size_t)(nbase + 64 + srl) * K + skofs;
    const ushort* gBl0 = Bl + (size_t)(nbase + srl) * K + skofs;
    const ushort* gBl1 = Bl + (size_t)(nbase + 64 + srl) * K + skofs;

    const int l0 = tid * 8;
    const int l1 = 2048 + tid * 8;

    const int lane = tid & 63;
    const int wid = tid >> 6;
    const int wr = (wid >> 1) * 64;
    const int wc = (wid & 1) * 64;
    const int lrow = lane & 15;
    const int g = lane >> 4;
    int aoff[4], boff[4];
    #pragma unroll
    for (int i = 0; i < 4; ++i) {
        int r = wr + i * 16 + lrow;
        aoff[i] = r * 32 + ((g ^ ((r >> 1) & 3)) << 3);
        int rn = wc + i * 16 + lrow;
        boff[i] = rn * 32 + ((g ^ ((rn >> 1) & 3)) << 3);
    }

    f32x4 acc[4][4];
    #pragma unroll
    for (int i = 0; i < 4; ++i)
        #pragma unroll
        for (int j = 0; j < 4; ++j)
            acc[i][j] = (f32x4){0.f, 0.f, 0.f, 0.f};

    const int ktiles = TRIK ? ((mbase + 128) >> 5) : (K >> 5);
    for (int kt = 0; kt < ktiles; ++kt) {
        GL16(gAh0, sAh + l0);  GL16(gAh1, sAh + l1);
        GL16(gAl0, sAl + l0);  GL16(gAl1, sAl + l1);
        GL16(gBh0, sBh + l0);  GL16(gBh1, sBh + l1);
        GL16(gBl0, sBl + l0);  GL16(gBl1, sBl + l1);
        gAh0 += 32; gAh1 += 32; gAl0 += 32; gAl1 += 32;
        gBh0 += 32; gBh1 += 32; gBl0 += 32; gBl1 += 32;
        __syncthreads();

        bf16x8 fBh[4], fBl[4];
        #pragma unroll
        for (int i = 0; i < 4; ++i) {
            fBh[i] = *(const bf16x8*)(sBh + boff[i]);
            fBl[i] = *(const bf16x8*)(sBl + boff[i]);
        }
        #pragma unroll
        for (int mi = 0; mi < 4; ++mi) {
            bf16x8 ah = *(const bf16x8*)(sAh + aoff[mi]);
            bf16x8 al = *(const bf16x8*)(sAl + aoff[mi]);
            #pragma unroll
            for (int ni = 0; ni < 4; ++ni) {
                acc[mi][ni] = __builtin_amdgcn_mfma_f32_16x16x32_bf16(ah, fBh[ni], acc[mi][ni], 0, 0, 0);
                acc[mi][ni] = __builtin_amdgcn_mfma_f32_16x16x32_bf16(ah, fBl[ni], acc[mi][ni], 0, 0, 0);
                acc[mi][ni] = __builtin_amdgcn_mfma_f32_16x16x32_bf16(al, fBh[ni], acc[mi][ni], 0, 0, 0);
            }
        }
        __syncthreads();
    }

    // C/D layout: col = lane&15, row = (lane>>4)*4 + reg  [m89-verified]
    if (OM == 0) {
        #pragma unroll
        for (int ni = 0; ni < 4; ++ni) {
            const int c = nbase + wc + ni * 16 + lrow;
            float bv = 0.f;
            if (HASB) bv = bias[c];
            #pragma unroll
            for (int mi = 0; mi < 4; ++mi) {
                #pragma unroll
                for (int rg = 0; rg < 4; ++rg) {
                    const int r = mbase + wr + mi * 16 + g * 4 + rg;
                    float vv = acc[mi][ni][rg];
                    if (HASDIV) vv /= denp[r];
                    if (HASB) vv += bv;
                    if (ACT == 1) vv = (vv > 0.f) ? (vv + 1.f) : __expf(vv);
                    Cf[(size_t)r * N + c] = vv;
                }
            }
        }
    } else {
        // LDS-bounce epilogue: scalar LDS writes (XOR-swizzled), b128 global
        // stores. Pass 1: hi (lo kept in acc). Pass 2: lo.
        #pragma unroll
        for (int ni = 0; ni < 4; ++ni) {
            const int cl = wc + ni * 16 + lrow;
            const int c = nbase + cl;
            float bv = 0.f;
            if (HASB) bv = bias[c];
            #pragma unroll
            for (int mi = 0; mi < 4; ++mi) {
                #pragma unroll
                for (int rg = 0; rg < 4; ++rg) {
                    const int rl = wr + mi * 16 + g * 4 + rg;
                    const int r = mbase + rl;
                    float vv = acc[mi][ni][rg];
                    if (HASDIV) vv /= denp[r];
                    if (HASB) vv += bv;
                    if (ACT == 1) vv = (vv > 0.f) ? (vv + 1.f) : __expf(vv);
                    if (CAUSAL && c > r) vv = 0.f;
                    unsigned short hb = f2bf(vv);
                    sU[rl * 128 + (cl ^ ((rl & 15) << 3))] = hb;
                    acc[mi][ni][rg] = vv - bf2f(hb);   // lo for pass 2
                }
            }
        }
        __syncthreads();
        const int orow = tid >> 1;
        const int ohalf = (tid & 1) << 6;
        const int oswz = (orow & 15) << 3;
        float rsum = 0.f;
        {
            const size_t gb = (size_t)(mbase + orow) * N + nbase;
            #pragma unroll
            for (int j = 0; j < 8; ++j) {
                const int cc = ohalf + j * 8;
                ushortx8 v8 = *(const ushortx8*)&sU[orow * 128 + (cc ^ oswz)];
                *(ushortx8*)&Ch[gb + cc] = v8;
                if (SUMROWS) {
                    #pragma unroll
                    for (int t = 0; t < 8; ++t) rsum += bf2f(v8[t]);
                }
            }
        }
        __syncthreads();
        #pragma unroll
        for (int ni = 0; ni < 4; ++ni) {
            const int cl = wc + ni * 16 + lrow;
            #pragma unroll
            for (int mi = 0; mi < 4; ++mi) {
                #pragma unroll
                for (int rg = 0; rg < 4; ++rg) {
                    const int rl = wr + mi * 16 + g * 4 + rg;
                    sU[rl * 128 + (cl ^ ((rl & 15) << 3))] = f2bf(acc[mi][ni][rg]);
                }
            }
        }
        __syncthreads();
        {
            const size_t gb = (size_t)(mbase + orow) * N + nbase;
            #pragma unroll
            for (int j = 0; j < 8; ++j) {
                const int cc = ohalf + j * 8;
                ushortx8 v8 = *(const ushortx8*)&sU[orow * 128 + (cc ^ oswz)];
                *(ushortx8*)&Cl[gb + cc] = v8;
                if (SUMROWS) {
                    #pragma unroll
                    for (int t = 0; t < 8; ++t) rsum += bf2f(v8[t]);
                }
            }
        }
        if (SUMROWS) atomicAdd(&denout[mbase + orow], rsum);
    }
}

// ---------------------------------------------------------------------------
// Fused QKV projection: A = emb hi/lo [4096][1024], B = Wqkv^T hi/lo
// [3072][1024]. nbase 0..7 -> q (elu+1), 8..15 -> k (elu+1), 16..23 -> v
// (linear, TRANSPOSED out [DIM][SEQ] per batch). All epilogues LDS-bounced.
// ---------------------------------------------------------------------------
__global__ __launch_bounds__(256, 2)
void qkvproj_kernel(const ushort* __restrict__ Ah, const ushort* __restrict__ Al,
                    const ushort* __restrict__ Bh, const ushort* __restrict__ Bl,
                    const float* __restrict__ bq, const float* __restrict__ bk,
                    const float* __restrict__ bv_,
                    ushort* __restrict__ qh, ushort* __restrict__ ql,
                    ushort* __restrict__ kh, ushort* __restrict__ kl,
                    ushort* __restrict__ vTh, ushort* __restrict__ vTl) {
    __shared__ __align__(16) ushort sU[16384];
    ushort* sAh = sU;
    ushort* sAl = sU + 4096;
    ushort* sBh = sU + 8192;
    ushort* sBl = sU + 12288;

    const int tid = threadIdx.x;
    const int ntn = 24;
    const int mbase = (blockIdx.x / ntn) << 7;
    const int nbase = (blockIdx.x % ntn) << 7;
    const int mode = nbase >> 10;             // 0 q, 1 k, 2 v (block-uniform)
    const int cb = nbase & 1023;

    const int srl = tid >> 2;
    const int schunk = (tid & 3) ^ ((tid >> 3) & 3);
    const size_t skofs = (size_t)schunk * 8;

    const ushort* gAh0 = Ah + (size_t)(mbase + srl) * DIM + skofs;
    const ushort* gAh1 = Ah + (size_t)(mbase + 64 + srl) * DIM + skofs;
    const ushort* gAl0 = Al + (size_t)(mbase + srl) * DIM + skofs;
    const ushort* gAl1 = Al + (size_t)(mbase + 64 + srl) * DIM + skofs;
    const ushort* gBh0 = Bh + (size_t)(nbase + srl) * DIM + skofs;
    const ushort* gBh1 = Bh + (size_t)(nbase + 64 + srl) * DIM + skofs;
    const ushort* gBl0 = Bl + (size_t)(nbase + srl) * DIM + skofs;
    const ushort* gBl1 = Bl + (size_t)(nbase + 64 + srl) * DIM + skofs;

    const int l0 = tid * 8;
    const int l1 = 2048 + tid * 8;

    const int lane = tid & 63;
    const int wid = tid >> 6;
    const int wr = (wid >> 1) * 64;
    const int wc = (wid & 1) * 64;
    const int lrow = lane & 15;
    const int g = lane >> 4;
    int aoff[4], boff[4];
    #pragma unroll
    for (int i = 0; i < 4; ++i) {
        int r = wr + i * 16 + lrow;
        aoff[i] = r * 32 + ((g ^ ((r >> 1) & 3)) << 3);
        int rn = wc + i * 16 + lrow;
        boff[i] = rn * 32 + ((g ^ ((rn >> 1) & 3)) << 3);
    }

    f32x4 acc[4][4];
    #pragma unroll
    for (int i = 0; i < 4; ++i)
        #pragma unroll
        for (int j = 0; j < 4; ++j)
            acc[i][j] = (f32x4){0.f, 0.f, 0.f, 0.f};

    for (int kt = 0; kt < DIM / 32; ++kt) {
        GL16(gAh0, sAh + l0);  GL16(gAh1, sAh + l1);
        GL16(gAl0, sAl + l0);  GL16(gAl1, sAl + l1);
        GL16(gBh0, sBh + l0);  GL16(gBh1, sBh + l1);
        GL16(gBl0, sBl + l0);  GL16(gBl1, sBl + l1);
        gAh0 += 32; gAh1 += 32; gAl0 += 32; gAl1 += 32;
        gBh0 += 32; gBh1 += 32; gBl0 += 32; gBl1 += 32;
        __syncthreads();

        bf16x8 fBh[4], fBl[4];
        #pragma unroll
        for (int i = 0; i < 4; ++i) {
            fBh[i] = *(const bf16x8*)(sBh + boff[i]);
            fBl[i] = *(const bf16x8*)(sBl + boff[i]);
        }
        #pragma unroll
        for (int mi = 0; mi < 4; ++mi) {
            bf16x8 ah = *(const bf16x8*)(sAh + aoff[mi]);
            bf16x8 al = *(const bf16x8*)(sAl + aoff[mi]);
            #pragma unroll
            for (int ni = 0; ni < 4; ++ni) {
                acc[mi][ni] = __builtin_amdgcn_mfma_f32_16x16x32_bf16(ah, fBh[ni], acc[mi][ni], 0, 0, 0);
                acc[mi][ni] = __builtin_amdgcn_mfma_f32_16x16x32_bf16(ah, fBl[ni], acc[mi][ni], 0, 0, 0);
                acc[mi][ni] = __builtin_amdgcn_mfma_f32_16x16x32_bf16(al, fBh[ni], acc[mi][ni], 0, 0, 0);
            }
        }
        __syncthreads();
    }

    const float* bias = (mode == 0) ? bq : (mode == 1) ? bk : bv_;

    if (mode < 2) {
        ushort* dh = (mode == 0) ? qh : kh;
        ushort* dl = (mode == 0) ? ql : kl;
        // row-major bounce
        #pragma unroll
        for (int ni = 0; ni < 4; ++ni) {
            const int cl = wc + ni * 16 + lrow;
            const float bvv = bias[cb + cl];
            #pragma unroll
            for (int mi = 0; mi < 4; ++mi) {
                #pragma unroll
                for (int rg = 0; rg < 4; ++rg) {
                    const int rl = wr + mi * 16 + g * 4 + rg;
                    float vv = acc[mi][ni][rg] + bvv;
                    vv = (vv > 0.f) ? (vv + 1.f) : __expf(vv);
                    unsigned short hb = f2bf(vv);
                    sU[rl * 128 + (cl ^ ((rl & 15) << 3))] = hb;
                    acc[mi][ni][rg] = vv - bf2f(hb);
                }
            }
        }
        __syncthreads();
        const int orow = tid >> 1;
        const int ohalf = (tid & 1) << 6;
        const int oswz = (orow & 15) << 3;
        {
            const size_t gb = (size_t)(mbase + orow) * DIM + cb;
            #pragma unroll
            for (int j = 0; j < 8; ++j) {
                const int cc = ohalf + j * 8;
                *(ushortx8*)&dh[gb + cc] =
                    *(const ushortx8*)&sU[orow * 128 + (cc ^ oswz)];
            }
        }
        __syncthreads();
        #pragma unroll
        for (int ni = 0; ni < 4; ++ni) {
            const int cl = wc + ni * 16 + lrow;
            #pragma unroll
            for (int mi = 0; mi < 4; ++mi) {
                #pragma unroll
                for (int rg = 0; rg < 4; ++rg) {
                    const int rl = wr + mi * 16 + g * 4 + rg;
                    sU[rl * 128 + (cl ^ ((rl & 15) << 3))] = f2bf(acc[mi][ni][rg]);
                }
            }
        }
        __syncthreads();
        {
            const size_t gb = (size_t)(mbase + orow) * DIM + cb;
            #pragma unroll
            for (int j = 0; j < 8; ++j) {
                const int cc = ohalf + j * 8;
                *(ushortx8*)&dl[gb + cc] =
                    *(const ushortx8*)&sU[orow * 128 + (cc ^ oswz)];
            }
        }
    } else {
        // transposed bounce: write sU[c][r], read rows of v^T vectorized
        #pragma unroll
        for (int ni = 0; ni < 4; ++ni) {
            const int cl = wc + ni * 16 + lrow;
            const float bvv = bias[cb + cl];
            #pragma unroll
            for (int mi = 0; mi < 4; ++mi) {
                #pragma unroll
                for (int rg = 0; rg < 4; ++rg) {
                    const int rl = wr + mi * 16 + g * 4 + rg;
                    float vv = acc[mi][ni][rg] + bvv;
                    unsigned short hb = f2bf(vv);
                    sU[cl * 128 + (rl ^ ((cl & 15) << 3))] = hb;
                    acc[mi][ni][rg] = vv - bf2f(hb);
                }
            }
        }
        __syncthreads();
        const int ocol = tid >> 1;                 // local dim index 0..127
        const int ohalf = (tid & 1) << 6;          // local seq half
        const int oswz = (ocol & 15) << 3;
        const int batch = mbase >> 11;
        const int s0 = mbase & (SEQ - 1);
        {
            const size_t gb = (size_t)batch * DIM * SEQ
                            + (size_t)(cb + ocol) * SEQ + s0;
            #pragma unroll
            for (int j = 0; j < 8; ++j) {
                const int rr = ohalf + j * 8;
                *(ushortx8*)&vTh[gb + rr] =
                    *(const ushortx8*)&sU[ocol * 128 + (rr ^ oswz)];
            }
        }
        __syncthreads();
        #pragma unroll
        for (int ni = 0; ni < 4; ++ni) {
            const int cl = wc + ni * 16 + lrow;
            #pragma unroll
            for (int mi = 0; mi < 4; ++mi) {
                #pragma unroll
                for (int rg = 0; rg < 4; ++rg) {
                    const int rl = wr + mi * 16 + g * 4 + rg;
                    sU[cl * 128 + (rl ^ ((cl & 15) << 3))] = f2bf(acc[mi][ni][rg]);
                }
            }
        }
        __syncthreads();
        {
            const size_t gb = (size_t)batch * DIM * SEQ
                            + (size_t)(cb + ocol) * SEQ + s0;
            #pragma unroll
            for (int j = 0; j < 8; ++j) {
                const int rr = ohalf + j * 8;
                *(ushortx8*)&vTl[gb + rr] =
                    *(const ushortx8*)&sU[ocol * 128 + (rr ^ oswz)];
            }
        }
    }
}

// ---------------------------------------------------------------------------
// Block reduce helper
// ---------------------------------------------------------------------------
__device__ __forceinline__ float block_reduce_sum(float v, float* red) {
    #pragma unroll
    for (int off = 32; off > 0; off >>= 1) v += __shfl_down(v, off);
    const int lane = threadIdx.x & 63;
    const int wid = threadIdx.x >> 6;
    if (lane == 0) red[wid] = v;
    __syncthreads();
    float s = red[0] + red[1] + red[2] + red[3];
    return s;
}

// fp32 den for fallback
__global__ __launch_bounds__(256)
void den_kernel(const float* __restrict__ scores, float* __restrict__ den) {
    const int row = blockIdx.x;
    const int b = row >> 11;
    const int i = row & (SEQ - 1);
    const float* r = scores + (size_t)b * SEQ * SEQ + (size_t)i * SEQ;
    float s = 0.f;
    for (int j = threadIdx.x * 4; j < SEQ; j += 256 * 4) {
        float4 v = *(const float4*)&r[j];
        s += v.x + v.y + v.z + v.w;
    }
    __shared__ float red[4];
    float tot = block_reduce_sum(s, red);
    if (threadIdx.x == 0) den[row] = tot + EPS_D;
}

// ---------------------------------------------------------------------------
// LayerNorm (reads fp32) -> hi/lo bf16 split only
// ---------------------------------------------------------------------------
__global__ __launch_bounds__(256)
void ln_split_kernel(const float* __restrict__ io,
                     const float* __restrict__ gamma,
                     const float* __restrict__ beta,
                     ushort* __restrict__ ahi,
                     ushort* __restrict__ alo) {
    const size_t row = blockIdx.x;
    const float* r = io + row * DIM;
    const int d = threadIdx.x * 4;
    float4 v = *(const float4*)&r[d];
    float s = v.x + v.y + v.z + v.w;
    float sq = v.x * v.x + v.y * v.y + v.z * v.z + v.w * v.w;
    __shared__ float r1[4];
    __shared__ float r2[4];
    float tot = block_reduce_sum(s, r1);
    __syncthreads();
    float totsq = block_reduce_sum(sq, r2);
    const float mu = tot * (1.f / DIM);
    const float var = totsq * (1.f / DIM) - mu * mu;
    const float rs = rsqrtf(var + LN_EPS);
    float4 gv = *(const float4*)&gamma[d];
    float4 bv = *(const float4*)&beta[d];
    v.x = (v.x - mu) * rs * gv.x + bv.x;
    v.y = (v.y - mu) * rs * gv.y + bv.y;
    v.z = (v.z - mu) * rs * gv.z + bv.z;
    v.w = (v.w - mu) * rs * gv.w + bv.w;
    ushort4 h, l;
    h.x = f2bf(v.x); l.x = f2bf(v.x - bf2f(h.x));
    h.y = f2bf(v.y); l.y = f2bf(v.y - bf2f(h.y));
    h.z = f2bf(v.z); l.z = f2bf(v.z - bf2f(h.z));
    h.w = f2bf(v.w); l.w = f2bf(v.w - bf2f(h.w));
    *(ushort4*)&ahi[row * DIM + d] = h;
    *(ushort4*)&alo[row * DIM + d] = l;
}

// fp32 LN (fallback)
__global__ __launch_bounds__(256)
void ln_kernel(float* __restrict__ io,
               const float* __restrict__ gamma,
               const float* __restrict__ beta) {
    const size_t row = blockIdx.x;
    float* r = io + row * DIM;
    const int d = threadIdx.x * 4;
    float4 v = *(const float4*)&r[d];
    float s = v.x + v.y + v.z + v.w;
    float sq = v.x * v.x + v.y * v.y + v.z * v.z + v.w * v.w;
    __shared__ float r1[4];
    __shared__ float r2[4];
    float tot = block_reduce_sum(s, r1);
    __syncthreads();
    float totsq = block_reduce_sum(sq, r2);
    const float mu = tot * (1.f / DIM);
    const float var = totsq * (1.f / DIM) - mu * mu;
    const float rs = rsqrtf(var + LN_EPS);
    float4 gv = *(const float4*)&gamma[d];
    float4 bv = *(const float4*)&beta[d];
    v.x = (v.x - mu) * rs * gv.x + bv.x;
    v.y = (v.y - mu) * rs * gv.y + bv.y;
    v.z = (v.z - mu) * rs * gv.z + bv.z;
    v.w = (v.w - mu) * rs * gv.w + bv.w;
    *(float4*)&r[d] = v;
}

// ---------------------------------------------------------------------------
// Logits kernel. XCD stripe swizzle + NEW epilogue: per-wave LDS bounce so
// every global store is a full 128-B line (kills L2 read-for-ownership on
// partial-line writes — the 570 MB FETCH excess). No barriers needed: each
// wave bounces its own 64x64 quadrant through its private 8 KB of the dead
// staging LDS, two 32-row passes.
// ---------------------------------------------------------------------------
__global__ __launch_bounds__(256, 2)
void logits_mfma_kernel(const ushort* __restrict__ Ahi,
                        const ushort* __restrict__ Alo,
                        const ushort* __restrict__ Bhi,
                        const ushort* __restrict__ Blo,
                        const float* __restrict__ bias,
                        float* __restrict__ C) {
    __shared__ __align__(16) ushort sU[16384];
    ushort* sAh = sU;
    ushort* sAl = sU + 4096;
    ushort* sBh = sU + 8192;
    ushort* sBl = sU + 12288;

    const int tid = threadIdx.x;
    const int bid = blockIdx.x;
    const int xcd = bid & 7;
    const int idx = bid >> 3;                 // 0..999
    const int mbase = ((xcd << 2) | (idx & 3)) * 128;  // 32 m-tiles
    const int nbase = (idx >> 2) * 128;                // 250 n-tiles

    const int srl = tid >> 2;
    const int schunk = (tid & 3) ^ ((tid >> 3) & 3);
    const size_t skofs = (size_t)schunk * 8;

    const ushort* gAh0 = Ahi + (size_t)(mbase + srl) * DIM + skofs;
    const ushort* gAh1 = Ahi + (size_t)(mbase + 64 + srl) * DIM + skofs;
    const ushort* gAl0 = Alo + (size_t)(mbase + srl) * DIM + skofs;
    const ushort* gAl1 = Alo + (size_t)(mbase + 64 + srl) * DIM + skofs;
    const ushort* gBh0 = Bhi + (size_t)(nbase + srl) * DIM + skofs;
    const ushort* gBh1 = Bhi + (size_t)(nbase + 64 + srl) * DIM + skofs;
    const ushort* gBl0 = Blo + (size_t)(nbase + srl) * DIM + skofs;
    const ushort* gBl1 = Blo + (size_t)(nbase + 64 + srl) * DIM + skofs;

    const int l0 = tid * 8;
    const int l1 = 2048 + tid * 8;

    const int lane = tid & 63;
    const int wid = tid >> 6;
    const int wr = (wid >> 1) * 64;
    const int wc = (wid & 1) * 64;
    const int lrow = lane & 15;
    const int g = lane >> 4;
    int aoff[4], boff[4];
    #pragma unroll
    for (int i = 0; i < 4; ++i) {
        int r = wr + i * 16 + lrow;
        aoff[i] = r * 32 + ((g ^ ((r >> 1) & 3)) << 3);
        int rn = wc + i * 16 + lrow;
        boff[i] = rn * 32 + ((g ^ ((rn >> 1) & 3)) << 3);
    }

    f32x4 acc[4][4];
    #pragma unroll
    for (int i = 0; i < 4; ++i)
        #pragma unroll
        for (int j = 0; j < 4; ++j)
            acc[i][j] = (f32x4){0.f, 0.f, 0.f, 0.f};

    for (int kt = 0; kt < DIM / 32; ++kt) {
        GL16(gAh0, sAh + l0);  GL16(gAh1, sAh + l1);
        GL16(gAl0, sAl + l0);  GL16(gAl1, sAl + l1);
        GL16(gBh0, sBh + l0);  GL16(gBh1, sBh + l1);
        GL16(gBl0, sBl + l0);  GL16(gBl1, sBl + l1);
        gAh0 += 32; gAh1 += 32; gAl0 += 32; gAl1 += 32;
        gBh0 += 32; gBh1 += 32; gBl0 += 32; gBl1 += 32;
        __syncthreads();

        bf16x8 fBh[4], fBl[4];
        #pragma unroll
        for (int i = 0; i < 4; ++i) {
            fBh[i] = *(const bf16x8*)(sBh + boff[i]);
            fBl[i] = *(const bf16x8*)(sBl + boff[i]);
        }
        #pragma unroll
        for (int mi = 0; mi < 4; ++mi) {
            bf16x8 ah = *(const bf16x8*)(sAh + aoff[mi]);
            bf16x8 al = *(const bf16x8*)(sAl + aoff[mi]);
            #pragma unroll
            for (int ni = 0; ni < 4; ++ni) {
                acc[mi][ni] = __builtin_amdgcn_mfma_f32_16x16x32_bf16(ah, fBh[ni], acc[mi][ni], 0, 0, 0);
                acc[mi][ni] = __builtin_amdgcn_mfma_f32_16x16x32_bf16(ah, fBl[ni], acc[mi][ni], 0, 0, 0);
                acc[mi][ni] = __builtin_amdgcn_mfma_f32_16x16x32_bf16(al, fBh[ni], acc[mi][ni], 0, 0, 0);
            }
        }
        __syncthreads();
    }

    // ---- full-line store epilogue (per-wave private 8 KB region) ----
    // Last K-loop barrier guarantees staging reads done; each wave only
    // touches its own region afterwards, so no further __syncthreads.
    float* sC = (float*)sU + wid * 2048;          // 32 rows x 64 cols fp32
    const int rsub = lane >> 3;                   // 0..7
    const int cq8 = lane & 7;                     // 0..7
    #pragma unroll
    for (int p = 0; p < 2; ++p) {
        #pragma unroll
        for (int ni = 0; ni < 4; ++ni) {
            const int c = nbase + wc + ni * 16 + lrow;
            const float bv = bias[c];
            #pragma unroll
            for (int mh = 0; mh < 2; ++mh) {
                const int mi = p * 2 + mh;
                #pragma unroll
                for (int rg = 0; rg < 4; ++rg) {
                    const int rloc = mh * 16 + g * 4 + rg;      // 0..31
                    sC[rloc * 64 + ni * 16 + lrow] = acc[mi][ni][rg] + bv;
                }
            }
        }
        #pragma unroll
        for (int sub = 0; sub < 4; ++sub) {
            const int rloc = sub * 8 + rsub;                    // 0..31
            const size_t gb = (size_t)(mbase + wr + p * 32 + rloc) * VOCAB
                            + nbase + wc;
            #pragma unroll
            for (int j = 0; j < 2; ++j) {
                const int cq = cq8 + j * 8;                     // 0..15
                f32x4 v4 = *(const f32x4*)&sC[rloc * 64 + cq * 4];
                __builtin_nontemporal_store(v4, (f32x4*)&C[gb + cq * 4]);
            }
        }
    }
}

// ---------------------------------------------------------------------------
// Fallback fp32 GEMM + scores (used only if workspace too small)
// ---------------------------------------------------------------------------
template<int ACT, bool HAS_BIAS, bool HAS_DIV>
__global__ __launch_bounds__(256)
void gemm_kernel(const float* __restrict__ A,
                 const float* __restrict__ B,
                 const float* __restrict__ bias,
                 const float* __restrict__ rowdiv,
                 float* __restrict__ C,
                 int M, int N, int K) {
    __shared__ float As[16][64];
    __shared__ float Bs[16][64];

    const int tid = threadIdx.x;
    const int tx = tid & 15;
    const int ty = tid >> 4;
    const int row0 = blockIdx.y * 64;
    const int col0 = blockIdx.x * 64;

    const int a_row = tid >> 2;
    const int a_col = (tid & 3) * 4;
    const int b_row = tid >> 4;
    const int b_col = (tid & 15) * 4;

    const float* Aptr = A + (size_t)(row0 + a_row) * K + a_col;
    const float* Bptr = B + (size_t)b_row * N + col0 + b_col;

    float acc[4][4];
    #pragma unroll
    for (int i = 0; i < 4; ++i)
        #pragma unroll
        for (int j = 0; j < 4; ++j) acc[i][j] = 0.f;

    for (int k0 = 0; k0 < K; k0 += 16) {
        float4 a4 = *(const float4*)(Aptr + k0);
        float4 b4 = *(const float4*)(Bptr + (size_t)k0 * N);
        As[a_col + 0][a_row] = a4.x;
        As[a_col + 1][a_row] = a4.y;
        As[a_col + 2][a_row] = a4.z;
        As[a_col + 3][a_row] = a4.w;
        *(float4*)&Bs[b_row][b_col] = b4;
        __syncthreads();
        #pragma unroll
        for (int kk = 0; kk < 16; ++kk) {
            float4 av = *(const float4*)&As[kk][ty * 4];
            float4 bv = *(const float4*)&Bs[kk][tx * 4];
            float am[4] = {av.x, av.y, av.z, av.w};
            float bm[4] = {bv.x, bv.y, bv.z, bv.w};
            #pragma unroll
            for (int i = 0; i < 4; ++i)
                #pragma unroll
                for (int j = 0; j < 4; ++j)
                    acc[i][j] = fmaf(am[i], bm[j], acc[i][j]);
        }
        __syncthreads();
    }

    #pragma unroll
    for (int i = 0; i < 4; ++i) {
        const int r = row0 + ty * 4 + i;
        float rdiv = 1.f;
        if (HAS_DIV) rdiv = 1.f / rowdiv[r];
        #pragma unroll
        for (int j = 0; j < 4; ++j) {
            const int c = col0 + tx * 4 + j;
            float v = acc[i][j] * rdiv;
            if (HAS_BIAS) v += bias[c];
            if (ACT == 1) v = (v > 0.f) ? (v + 1.f) : __expf(v);
            C[(size_t)r * N + c] = v;
        }
    }
}

__global__ __launch_bounds__(256)
void scores_kernel(const float* __restrict__ q,
                   const float* __restrict__ k,
                   float* __restrict__ scores) {
    const int b = blockIdx.z;
    const int tid = threadIdx.x;
    const int tx = tid & 15;
    const int ty = tid >> 4;
    const int i0 = blockIdx.y * 64;
    const int j0 = blockIdx.x * 64;
    float* Sc = scores + (size_t)b * SEQ * SEQ;

    if (j0 > i0 + 63) {
        #pragma unroll
        for (int i = 0; i < 4; ++i)
            #pragma unroll
            for (int j = 0; j < 4; ++j)
                Sc[(size_t)(i0 + ty * 4 + i) * SEQ + j0 + tx * 4 + j] = 0.f;
        return;
    }

    const float* Q = q + (size_t)b * SEQ * DIM;
    const float* Kp = k + (size_t)b * SEQ * DIM;

    __shared__ float Qs[16][64];
    __shared__ float Ks[16][64];

    const int l_row = tid >> 2;
    const int l_col = (tid & 3) * 4;

    const float* Qptr = Q + (size_t)(i0 + l_row) * DIM + l_col;
    const float* Kptr = Kp + (size_t)(j0 + l_row) * DIM + l_col;

    float acc[4][4];
    #pragma unroll
    for (int i = 0; i < 4; ++i)
        #pragma unroll
        for (int j = 0; j < 4; ++j) acc[i][j] = 0.f;

    for (int d0 = 0; d0 < DIM; d0 += 16) {
        float4 a4 = *(const float4*)(Qptr + d0);
        float4 b4 = *(const float4*)(Kptr + d0);
        Qs[l_col + 0][l_row] = a4.x;
        Qs[l_col + 1][l_row] = a4.y;
        Qs[l_col + 2][l_row] = a4.z;
        Qs[l_col + 3][l_row] = a4.w;
        Ks[l_col + 0][l_row] = b4.x;
        Ks[l_col + 1][l_row] = b4.y;
        Ks[l_col + 2][l_row] = b4.z;
        Ks[l_col + 3][l_row] = b4.w;
        __syncthreads();
        #pragma unroll
        for (int kk = 0; kk < 16; ++kk) {
            float4 av = *(const float4*)&Qs[kk][ty * 4];
            float4 bv = *(const float4*)&Ks[kk][tx * 4];
            float am[4] = {av.x, av.y, av.z, av.w};
            float bm[4] = {bv.x, bv.y, bv.z, bv.w};
            #pragma unroll
            for (int i = 0; i < 4; ++i)
                #pragma unroll
                for (int j = 0; j < 4; ++j)
                    acc[i][j] = fmaf(am[i], bm[j], acc[i][j]);
        }
        __syncthreads();
    }

    #pragma unroll
    for (int i = 0; i < 4; ++i) {
        const int ii = i0 + ty * 4 + i;
        #pragma unroll
        for (int j = 0; j < 4; ++j) {
            const int jj = j0 + tx * 4 + j;
            Sc[(size_t)ii * SEQ + jj] = (jj <= ii) ? acc[i][j] : 0.f;
        }
    }
}

// ---------------------------------------------------------------------------
// Host launch
// ---------------------------------------------------------------------------
extern "C" void kernel_launch(void* const* d_in, const int* in_sizes, int n_in,
                              void* d_out, int out_size, void* d_ws, size_t ws_size,
                              hipStream_t stream) {
    const int*   x     = (const int*)d_in[0];
    const float* table = (const float*)d_in[1];
    const float* Wq    = (const float*)d_in[2];
    const float* bq    = (const float*)d_in[3];
    const float* Wk    = (const float*)d_in[4];
    const float* bk    = (const float*)d_in[5];
    const float* Wv    = (const float*)d_in[6];
    const float* bv    = (const float*)d_in[7];
    const float* Wo    = (const float*)d_in[8];
    const float* bo    = (const float*)d_in[9];
    const float* gamma = (const float*)d_in[10];
    const float* beta  = (const float*)d_in[11];
    const float* Wout  = (const float*)d_in[12];
    const float* bout  = (const float*)d_in[13];
    float* logits = (float*)d_out;

    const int M = BATCH * SEQ;                 // 4096

    // ---- workspace layout (identical to round-5 proven budget)
    char* p = (char*)d_ws;
    auto alloc = [&](size_t bytes) { char* r = p; p += bytes; return r; };
    ushort* WoutTh = (ushort*)alloc((size_t)VOCAB * DIM * 2);   // 65.5 MB
    ushort* WoutTl = (ushort*)alloc((size_t)VOCAB * DIM * 2);
    ushort* ehi    = (ushort*)alloc((size_t)M * DIM * 2);       // 8.39 MB
    ushort* elo    = (ushort*)alloc((size_t)M * DIM * 2);
    ushort* WqkvTh = (ushort*)alloc((size_t)3 * DIM * DIM * 2); // concat q|k|v
    ushort* WqkvTl = (ushort*)alloc((size_t)3 * DIM * DIM * 2);
    ushort* WoTh   = (ushort*)alloc((size_t)DIM * DIM * 2);
    ushort* WoTl   = (ushort*)alloc((size_t)DIM * DIM * 2);
    ushort* qhi    = (ushort*)alloc((size_t)M * DIM * 2);
    ushort* qlo    = (ushort*)alloc((size_t)M * DIM * 2);
    ushort* khi    = (ushort*)alloc((size_t)M * DIM * 2);
    ushort* klo    = (ushort*)alloc((size_t)M * DIM * 2);
    ushort* vTh    = (ushort*)alloc((size_t)BATCH * DIM * SEQ * 2);
    ushort* vTl    = (ushort*)alloc((size_t)BATCH * DIM * SEQ * 2);
    ushort* shi    = (ushort*)alloc((size_t)BATCH * SEQ * SEQ * 2); // 16.8 MB
    ushort* slo    = (ushort*)alloc((size_t)BATCH * SEQ * SEQ * 2);
    float*  den    = (float*)alloc((size_t)M * 4);
    const size_t need = (size_t)(p - (char*)d_ws);

    // aliases (liveness-checked): q dead after scores, k dead after scores,
    // e dead after qkv-proj
    ushort* attnh = qhi;
    ushort* attnl = qlo;
    float*  outf  = (float*)khi;               // spans khi+klo = 16.78 MB
    ushort* ahi   = ehi;
    ushort* alo   = elo;

    if (ws_size >= need) {
        // ---- MFMA pipeline ----
        // 0. ALL weight transpose+splits in one launch
        wsplit_all_kernel<<<8000 + 1024, 256, 0, stream>>>(
            Wq, Wk, Wv, Wo, Wout, WqkvTh, WqkvTl, WoTh, WoTl, WoutTh, WoutTl);

        // 1. embedding + local context -> hi/lo (also seeds den = EPS)
        embed_split_kernel<<<M, 256, 0, stream>>>(x, table, ehi, elo, den);

        // 2. fused q,k,v projection (one launch, 768 blocks)
        qkvproj_kernel<<<(M / 128) * 24, 256, 0, stream>>>(
            ehi, elo, WqkvTh, WqkvTl, bq, bk, bv,
            qhi, qlo, khi, klo, vTh, vTl);

        // 3. causal scores (hi/lo out) + den via per-tile row-sum atomics
        mfma3_kernel<0, false, false, true, false, true, 1>
            <<<dim3((SEQ / 128) * (SEQ / 128), BATCH), 256, 0, stream>>>(
            qhi, qlo, khi, klo, nullptr, nullptr, den, nullptr, shi, slo,
            SEQ, SEQ, DIM,
            (long long)SEQ * DIM, (long long)SEQ * DIM, (long long)SEQ * SEQ,
            (long long)SEQ);

        // 4. num = scores @ v / den  (triangular K-stop; attn hi/lo out)
        mfma3_kernel<0, false, true, false, true, false, 1>
            <<<dim3((SEQ / 128) * (DIM / 128), BATCH), 256, 0, stream>>>(
            shi, slo, vTh, vTl, nullptr, den, nullptr, nullptr, attnh, attnl,
            SEQ, DIM, SEQ,
            (long long)SEQ * SEQ, (long long)DIM * SEQ, (long long)SEQ * DIM,
            (long long)SEQ);

        // 5. out = attn @ Wo + bo  (fp32 out for LN)
        mfma3_kernel<0, true, false, false, false, false, 0>
            <<<dim3((M / 128) * (DIM / 128), 1), 256, 0, stream>>>(
            attnh, attnl, WoTh, WoTl, bo, nullptr, nullptr, outf, nullptr, nullptr,
            M, DIM, DIM, 0, 0, 0, 0);

        // 6. LayerNorm -> hi/lo split
        ln_split_kernel<<<M, 256, 0, stream>>>(outf, gamma, beta, ahi, alo);

        // 7. logits (XCD stripe swizzle + full-line store epilogue)
        logits_mfma_kernel<<<(M / 128) * (VOCAB / 128), 256, 0, stream>>>(
            ahi, alo, WoutTh, WoutTl, bout, logits);
    } else {
        // ---- fp32 fallback pipeline (never expected; safety) ----
        const size_t NE = (size_t)M * DIM;
        float* ws    = (float*)d_ws;
        float* emb   = ws;
        float* q     = ws + NE;
        float* k     = ws + 2 * NE;
        float* v     = ws + 3 * NE;
        float* sc    = ws + 4 * NE;
        float* denf  = sc + (size_t)BATCH * SEQ * SEQ;
        float* attn  = emb;
        float* out   = q;

        embed_ctx_kernel<<<M, 256, 0, stream>>>(x, table, emb);
        dim3 gq(DIM / 64, M / 64);
        gemm_kernel<1, true, false><<<gq, 256, 0, stream>>>(emb, Wq, bq, nullptr, q, M, DIM, DIM);
        gemm_kernel<1, true, false><<<gq, 256, 0, stream>>>(emb, Wk, bk, nullptr, k, M, DIM, DIM);
        gemm_kernel<0, true, false><<<gq, 256, 0, stream>>>(emb, Wv, bv, nullptr, v, M, DIM, DIM);
        dim3 gs(SEQ / 64, SEQ / 64, BATCH);
        scores_kernel<<<gs, 256, 0, stream>>>(q, k, sc);
        den_kernel<<<M, 256, 0, stream>>>(sc, denf);
        dim3 gn(DIM / 64, SEQ / 64);
        for (int b = 0; b < BATCH; ++b) {
            gemm_kernel<0, false, true><<<gn, 256, 0, stream>>>(
                sc + (size_t)b * SEQ * SEQ, v + (size_t)b * SEQ * DIM,
                nullptr, denf + (size_t)b * SEQ,
                attn + (size_t)b * SEQ * DIM, SEQ, DIM, SEQ);
        }
        gemm_kernel<0, true, false><<<gq, 256, 0, stream>>>(attn, Wo, bo, nullptr, out, M, DIM, DIM);
        ln_kernel<<<M, 256, 0, stream>>>(out, gamma, beta);
        dim3 gl(VOCAB / 64, M / 64);
        gemm_kernel<0, true, false><<<gl, 256, 0, stream>>>(out, Wout, bout, nullptr, logits, M, VOCAB, DIM);
    }
}